// Round 2
// baseline (511.637 us; speedup 1.0000x reference)
//
#include <hip/hip_runtime.h>

// Starlet 2D, four per-scale launches (exact reference cascade semantics).
// Per-scale kernel: 64x64 output tile, halo 2D (x-halo rounded up to vec4),
// float4 global+LDS throughout, residue-class 4-row register blocking in the
// vertical pass (8 b128 reads -> 4 vec4 outputs), static one-task-per-thread
// v-pass. LDS 38-65 KB -> 2-4 blocks/CU for latency hiding.

constexpr int H  = 1024, W = 1024;
constexpr int TS = 64;
constexpr int NT = 256;

template<int D> struct Cfg {
    static constexpr int RY   = 2 * D;              // exact vertical halo
    static constexpr int RXV  = (2 * D + 3) / 4;    // x-halo in vec4 (1,1,2,4)
    static constexpr int RX   = 4 * RXV;            // x-halo floats (4,4,8,16)
    static constexpr int ROWS = TS + 2 * RY;        // 68,72,80,96
    static constexpr int AV   = 16 + 2 * RXV;       // region width vec4 (18,18,20,24)
    static constexpr int AS   = AV + 1;             // A row stride vec4 (pad)
    static constexpr int BS   = 17;                 // htmp row stride vec4 (16+1)
    static constexpr int LOGD = (D == 1) ? 0 : (D == 2) ? 1 : (D == 4) ? 2 : 3;
};

__device__ __forceinline__ int reflect_i(int g, int n) {
    g = (g < 0) ? -g : g;
    return (g >= n) ? (2 * n - 2 - g) : g;
}

template<int D>
__global__ __launch_bounds__(256, 4)
void starlet_scale(const float* __restrict__ in, long in_bs,
                   float* __restrict__ det,      long det_bs,
                   float* __restrict__ coa,      long coa_bs)
{
    using C = Cfg<D>;
    __shared__ float4 A4[C::ROWS * C::AS];   // input region (coarse_s)
    __shared__ float4 B4[C::ROWS * C::BS];   // horizontal-pass result

    static_assert(sizeof(float4) * (C::ROWS * C::AS + C::ROWS * C::BS) <= 160 * 1024, "LDS");

    const int tid = threadIdx.x;
    const int bx  = blockIdx.x * TS;
    const int by  = blockIdx.y * TS;
    const int b   = blockIdx.z;
    const float* __restrict__ inp = in + (long)b * in_bs;

    const float k0 = 0.0625f, k1 = 0.25f, k2 = 0.375f;

    // ---- Phase 1: load region rows [by-RY, by+64+RY) x cols [bx-RX, bx+64+RX) ----
    const bool interior = (bx >= C::RX) && (bx + TS + C::RX <= W) &&
                          (by >= C::RY) && (by + TS + C::RY <= H);
    if (interior) {
        const float* src = inp + (long)(by - C::RY) * W + (bx - C::RX);  // 16B aligned
        for (int i = tid; i < C::ROWS * C::AV; i += NT) {
            int r = i / C::AV, c = i - r * C::AV;
            A4[r * C::AS + c] = *(const float4*)(src + (long)r * W + 4 * c);
        }
    } else {
        float* Af = (float*)A4;
        for (int i = tid; i < C::ROWS * 4 * C::AV; i += NT) {
            int r  = i / (4 * C::AV), c = i - r * (4 * C::AV);
            int gy = reflect_i(by - C::RY + r, H);
            int gx = reflect_i(bx - C::RX + c, W);
            Af[r * (4 * C::AS) + c] = inp[(long)gy * W + gx];
        }
    }
    __syncthreads();

    // ---- Phase 2: horizontal 5-tap (dilated), all ROWS rows x 16 vec4 out cols ----
    for (int i = tid; i < C::ROWS * 16; i += NT) {
        int r = i >> 4, q = i & 15;
        int base = r * C::AS + C::RXV + q;
        float4 o;
        if constexpr (D >= 4) {
            constexpr int s = D / 4;                 // tap stride in vec4 (1 or 2)
            float4 t0 = A4[base - 2 * s], t1 = A4[base - s], t2 = A4[base];
            float4 t3 = A4[base + s],     t4 = A4[base + 2 * s];
            o.x = k0 * (t0.x + t4.x) + k1 * (t1.x + t3.x) + k2 * t2.x;
            o.y = k0 * (t0.y + t4.y) + k1 * (t1.y + t3.y) + k2 * t2.y;
            o.z = k0 * (t0.z + t4.z) + k1 * (t1.z + t3.z) + k2 * t2.z;
            o.w = k0 * (t0.w + t4.w) + k1 * (t1.w + t3.w) + k2 * t2.w;
        } else {
            float4 v0 = A4[base - 1], v1 = A4[base], v2 = A4[base + 1];
            float f[12] = {v0.x, v0.y, v0.z, v0.w,
                           v1.x, v1.y, v1.z, v1.w,
                           v2.x, v2.y, v2.z, v2.w};
            float oo[4];
            #pragma unroll
            for (int j = 0; j < 4; ++j) {
                if constexpr (D == 1)
                    oo[j] = k0 * (f[j + 2] + f[j + 6]) + k1 * (f[j + 3] + f[j + 5]) + k2 * f[j + 4];
                else
                    oo[j] = k0 * (f[j]     + f[j + 8]) + k1 * (f[j + 2] + f[j + 6]) + k2 * f[j + 4];
            }
            o.x = oo[0]; o.y = oo[1]; o.z = oo[2]; o.w = oo[3];
        }
        B4[r * C::BS + q] = o;
    }
    __syncthreads();

    // ---- Phase 3: vertical 5-tap, residue-class 4-row blocking, 1 task/thread ----
    // 16 groups x 16 vec4-cols = 256 tasks. Group u -> class c = u&(D-1), g = u>>logD.
    // Output rows y = c + (4g+k)*D, k=0..3 share taps: 8 reads -> 4 vec4 outputs.
    {
        const int q = tid & 15;
        const int u = tid >> 4;
        const int c = u & (D - 1);
        const int g = u >> C::LOGD;
        const int r0 = c + 4 * g * D;                // = RY + c + (4g-2)*D (RY=2D cancels)

        float4 rr[8];
        #pragma unroll
        for (int m = 0; m < 8; ++m)
            rr[m] = B4[(r0 + m * D) * C::BS + q];

        float* detp = det + (long)b * det_bs;
        float* coap = coa + (long)b * coa_bs;

        #pragma unroll
        for (int k = 0; k < 4; ++k) {
            float4 acc;
            acc.x = k0 * (rr[k].x + rr[k+4].x) + k1 * (rr[k+1].x + rr[k+3].x) + k2 * rr[k+2].x;
            acc.y = k0 * (rr[k].y + rr[k+4].y) + k1 * (rr[k+1].y + rr[k+3].y) + k2 * rr[k+2].y;
            acc.z = k0 * (rr[k].z + rr[k+4].z) + k1 * (rr[k+1].z + rr[k+3].z) + k2 * rr[k+2].z;
            acc.w = k0 * (rr[k].w + rr[k+4].w) + k1 * (rr[k+1].w + rr[k+3].w) + k2 * rr[k+2].w;

            const int y = c + (4 * g + k) * D;       // output row in [0,64)
            float4 old = A4[(C::RY + y) * C::AS + C::RXV + q];
            float4 d;
            d.x = old.x - acc.x; d.y = old.y - acc.y;
            d.z = old.z - acc.z; d.w = old.w - acc.w;

            const long gofs = (long)(by + y) * W + (bx + 4 * q);
            *(float4*)(detp + gofs) = d;
            *(float4*)(coap + gofs) = acc;
        }
    }
}

extern "C" void kernel_launch(void* const* d_in, const int* in_sizes, int n_in,
                              void* d_out, int out_size, void* d_ws, size_t ws_size,
                              hipStream_t stream) {
    const float* x = (const float*)d_in[0];
    float* out = (float*)d_out;
    float* ws  = (float*)d_ws;   // 16*1024*1024 floats = 64 MiB
    (void)in_sizes; (void)n_in; (void)ws_size; (void)out_size;

    const long HW = 1024L * 1024L;
    const long OB = 5 * HW;      // out per-batch stride (5 channels)

    dim3 grid(W / TS, H / TS, 16);
    dim3 block(NT);

    // s=0 (d=1): x -> detail ch0, coarse1 -> ws
    starlet_scale<1><<<grid, block, 0, stream>>>(x, HW, out + 0 * HW, OB, ws, HW);
    // s=1 (d=2): ws -> detail ch1, coarse2 -> out ch4 (temp stash)
    starlet_scale<2><<<grid, block, 0, stream>>>(ws, HW, out + 1 * HW, OB, out + 4 * HW, OB);
    // s=2 (d=4): out ch4 -> detail ch2, coarse3 -> ws
    starlet_scale<4><<<grid, block, 0, stream>>>(out + 4 * HW, OB, out + 2 * HW, OB, ws, HW);
    // s=3 (d=8): ws -> detail ch3, coarse4 -> out ch4 (final)
    starlet_scale<8><<<grid, block, 0, stream>>>(ws, HW, out + 3 * HW, OB, out + 4 * HW, OB);
}

// Round 3
// 503.884 us; speedup vs baseline: 1.0154x; 1.0154x over previous
//
#include <hip/hip_runtime.h>

// Starlet 2D: pair-fused scales {0,1} and {2,3}. Cascade intermediate
// (coarse1 / coarse3) lives entirely in LDS, pyramid-exact halos.
// Traffic: 768 MB (4-launch) -> ~512 MB. Kernel A 3 blocks/CU, B 2 blocks/CU.
// Symmetric-kernel x reflect-extension commutation => per-region reflect at
// load is exact (validated round 1, identical absmax).

constexpr int H = 1024, W = 1024;
constexpr long HW = (long)H * W;
constexpr long OB = 5 * HW;
constexpr int NT = 256;

__device__ __forceinline__ int reflect_i(int g, int n) {
    g = (g < 0) ? -g : g;
    return (g >= n) ? (2 * n - 2 - g) : g;
}

// XCD-chunked bijective swizzle: consecutive resident blocks on one XCD
// become spatial neighbors (halo reuse in that XCD's L2). nwg % 8 == 0.
__device__ __forceinline__ void swizzle_wg(int gx, int gy, int& tx, int& ty, int& tb) {
    const int nwg = gx * gy * (int)gridDim.z;
    const int lin = (int)blockIdx.x + gx * ((int)blockIdx.y + gy * (int)blockIdx.z);
    const int work = (lin & 7) * (nwg >> 3) + (lin >> 3);
    tx = work % gx;
    const int rest = work / gx;
    ty = rest % gy;
    tb = rest / gy;
}

__device__ __forceinline__ float4 f4sub(float4 a, float4 b) {
    return float4{a.x - b.x, a.y - b.y, a.z - b.z, a.w - b.w};
}

// ---------------- Kernel A: scales 0 (D=1) and 1 (D=2), tile 64x64 ----------------
// Region: y [-6,70) (76 rows) x floats [-8,72) (20 vec4). A stride 21, B stride 19.
__global__ __launch_bounds__(256, 3)
void starlet_s01(const float* __restrict__ in, float* __restrict__ out, float* __restrict__ ws)
{
    constexpr int ROWS = 76, AV = 20, SA = 21, SB = 19;
    __shared__ float4 A4[ROWS * SA];   // 25,536 B : x region, later coarse1 in place
    __shared__ float4 B4[ROWS * SB];   // 23,104 B : htmp
    const float k0 = 0.0625f, k1 = 0.25f, k2 = 0.375f;

    int tx, ty, tb;
    swizzle_wg(16, 16, tx, ty, tb);
    const int bx = tx * 64, by = ty * 64;
    const int tid = threadIdx.x;
    const float* __restrict__ inp = in + (long)tb * HW;

    // ---- phase 1: load x region ----
    if (bx >= 8 && bx + 72 <= W && by >= 6 && by + 70 <= H) {
        const float* src = inp + (long)(by - 6) * W + (bx - 8);   // 16B aligned
        for (int t = tid; t < ROWS * AV; t += NT) {
            int r = t / AV, c = t - r * AV;
            A4[r * SA + c] = *(const float4*)(src + (long)r * W + 4 * c);
        }
    } else {
        float* Af = (float*)A4;
        for (int t = tid; t < ROWS * 4 * AV; t += NT) {
            int r = t / (4 * AV), c = t - r * (4 * AV);
            Af[r * (4 * SA) + c] = inp[(long)reflect_i(by - 6 + r, H) * W + reflect_i(bx - 8 + c, W)];
        }
    }
    __syncthreads();

    // ---- s0 h-pass (D=1): all 76 rows, out float x = -4+4h, h in [0,18) ----
    for (int t = tid; t < ROWS * 18; t += NT) {
        int r = t / 18, h = t - r * 18;
        float4 v0 = A4[r * SA + h], v1 = A4[r * SA + h + 1], v2 = A4[r * SA + h + 2];
        float f[12] = {v0.x, v0.y, v0.z, v0.w, v1.x, v1.y, v1.z, v1.w, v2.x, v2.y, v2.z, v2.w};
        float4 o;
        o.x = k0 * (f[2] + f[6]) + k1 * (f[3] + f[5]) + k2 * f[4];
        o.y = k0 * (f[3] + f[7]) + k1 * (f[4] + f[6]) + k2 * f[5];
        o.z = k0 * (f[4] + f[8]) + k1 * (f[5] + f[7]) + k2 * f[6];
        o.w = k0 * (f[5] + f[9]) + k1 * (f[6] + f[8]) + k2 * f[7];
        B4[r * SB + h] = o;
    }
    __syncthreads();

    // ---- s0 v-pass: coarse1 on y [-4,68) -> A in place; det0 on central ----
    {
        float* det0 = out + (long)tb * OB;
        for (int t = tid; t < 18 * 18; t += NT) {
            int g = t / 18, h = t - g * 18;
            float4 rr[8];
            #pragma unroll
            for (int m = 0; m < 8; ++m) rr[m] = B4[(4 * g + m) * SB + h];
            #pragma unroll
            for (int k = 0; k < 4; ++k) {
                float4 c1;
                c1.x = k0 * (rr[k].x + rr[k+4].x) + k1 * (rr[k+1].x + rr[k+3].x) + k2 * rr[k+2].x;
                c1.y = k0 * (rr[k].y + rr[k+4].y) + k1 * (rr[k+1].y + rr[k+3].y) + k2 * rr[k+2].y;
                c1.z = k0 * (rr[k].z + rr[k+4].z) + k1 * (rr[k+1].z + rr[k+3].z) + k2 * rr[k+2].z;
                c1.w = k0 * (rr[k].w + rr[k+4].w) + k1 * (rr[k+1].w + rr[k+3].w) + k2 * rr[k+2].w;
                const int y = 4 * g + k - 4;             // [-4,68)
                const int slot = (y + 6) * SA + h + 1;
                float4 old = A4[slot];                    // x (own slot only: no race)
                A4[slot] = c1;
                if (y >= 0 && y < 64 && h >= 1 && h < 17)
                    *(float4*)(det0 + (long)(by + y) * W + bx + 4 * h - 4) = f4sub(old, c1);
            }
        }
    }
    __syncthreads();

    // ---- s1 h-pass (D=2): coarse1 rows [-4,68) (A rows 2..73), out x = 4*h1 ----
    for (int t = tid; t < 72 * 16; t += NT) {
        int r = t / 16, h1 = t - r * 16;
        int base = (r + 2) * SA + h1 + 1;
        float4 v0 = A4[base], v1 = A4[base + 1], v2 = A4[base + 2];
        float f[12] = {v0.x, v0.y, v0.z, v0.w, v1.x, v1.y, v1.z, v1.w, v2.x, v2.y, v2.z, v2.w};
        float4 o;
        o.x = k0 * (f[0] + f[8])  + k1 * (f[2] + f[6])  + k2 * f[4];
        o.y = k0 * (f[1] + f[9])  + k1 * (f[3] + f[7])  + k2 * f[5];
        o.z = k0 * (f[2] + f[10]) + k1 * (f[4] + f[8])  + k2 * f[6];
        o.w = k0 * (f[3] + f[11]) + k1 * (f[5] + f[9])  + k2 * f[7];
        B4[(r + 2) * SB + h1] = o;
    }
    __syncthreads();

    // ---- s1 v-pass (D=2): 256 groups, exactly one per thread ----
    {
        const int h1 = tid & 15, u = tid >> 4;
        const int c = u & 1, g = u >> 1;                 // c in [0,2), g in [0,8)
        float4 rr[8];
        #pragma unroll
        for (int m = 0; m < 8; ++m) rr[m] = B4[(2 + c + 8 * g + 2 * m) * SB + h1];
        float* det1 = out + (long)tb * OB + HW;
        float* coa  = ws + (long)tb * HW;
        #pragma unroll
        for (int k = 0; k < 4; ++k) {
            float4 c2;
            c2.x = k0 * (rr[k].x + rr[k+4].x) + k1 * (rr[k+1].x + rr[k+3].x) + k2 * rr[k+2].x;
            c2.y = k0 * (rr[k].y + rr[k+4].y) + k1 * (rr[k+1].y + rr[k+3].y) + k2 * rr[k+2].y;
            c2.z = k0 * (rr[k].z + rr[k+4].z) + k1 * (rr[k+1].z + rr[k+3].z) + k2 * rr[k+2].z;
            c2.w = k0 * (rr[k].w + rr[k+4].w) + k1 * (rr[k+1].w + rr[k+3].w) + k2 * rr[k+2].w;
            const int y = c + 2 * (4 * g + k);           // [0,64)
            float4 old = A4[(y + 6) * SA + h1 + 2];      // coarse1
            const long gofs = (long)(by + y) * W + bx + 4 * h1;
            *(float4*)(det1 + gofs) = f4sub(old, c2);
            *(float4*)(coa + gofs) = c2;
        }
    }
}

// ---------------- Kernel B: scales 2 (D=4) and 3 (D=8), tile 32x64 ----------------
// Region: y [-24,88) (112 rows) x floats [-24,56) (20 vec4). A stride 21, B stride 17.
__global__ __launch_bounds__(256, 2)
void starlet_s23(const float* __restrict__ in, float* __restrict__ out)
{
    constexpr int ROWS = 112, AV = 20, SA = 21, SB = 17;
    __shared__ float4 A4[ROWS * SA];   // 37,632 B : coarse2 region, later coarse3 in place
    __shared__ float4 B4[ROWS * SB];   // 30,464 B : htmp
    const float k0 = 0.0625f, k1 = 0.25f, k2 = 0.375f;

    int tx, ty, tb;
    swizzle_wg(32, 16, tx, ty, tb);
    const int bx = tx * 32, by = ty * 64;
    const int tid = threadIdx.x;
    const float* __restrict__ inp = in + (long)tb * HW;

    // ---- phase 1: load coarse2 region ----
    if (bx >= 24 && bx + 56 <= W && by >= 24 && by + 88 <= H) {
        const float* src = inp + (long)(by - 24) * W + (bx - 24);  // 16B aligned
        for (int t = tid; t < ROWS * AV; t += NT) {
            int r = t / AV, c = t - r * AV;
            A4[r * SA + c] = *(const float4*)(src + (long)r * W + 4 * c);
        }
    } else {
        float* Af = (float*)A4;
        for (int t = tid; t < ROWS * 4 * AV; t += NT) {
            int r = t / (4 * AV), c = t - r * (4 * AV);
            Af[r * (4 * SA) + c] = inp[(long)reflect_i(by - 24 + r, H) * W + reflect_i(bx - 24 + c, W)];
        }
    }
    __syncthreads();

    // ---- s2 h-pass (D=4, vec4-aligned taps): all 112 rows, out x = -16+4h ----
    for (int t = tid; t < ROWS * 16; t += NT) {
        int r = t / 16, h = t - r * 16;
        int base = r * SA + h;
        float4 t0 = A4[base], t1 = A4[base + 1], t2 = A4[base + 2], t3 = A4[base + 3], t4 = A4[base + 4];
        float4 o;
        o.x = k0 * (t0.x + t4.x) + k1 * (t1.x + t3.x) + k2 * t2.x;
        o.y = k0 * (t0.y + t4.y) + k1 * (t1.y + t3.y) + k2 * t2.y;
        o.z = k0 * (t0.z + t4.z) + k1 * (t1.z + t3.z) + k2 * t2.z;
        o.w = k0 * (t0.w + t4.w) + k1 * (t1.w + t3.w) + k2 * t2.w;
        B4[r * SB + h] = o;
    }
    __syncthreads();

    // ---- s2 v-pass: coarse3 on y [-16,80) -> A in place; det2 on central ----
    {
        float* det2 = out + (long)tb * OB + 2 * HW;
        for (int t = tid; t < 384; t += NT) {
            int h = t & 15, u = t >> 4;                  // u in [0,24)
            int c = u & 3, g = u >> 2;                   // c in [0,4), g in [0,6)
            float4 rr[8];
            #pragma unroll
            for (int m = 0; m < 8; ++m) rr[m] = B4[(c + 16 * g + 4 * m) * SB + h];
            #pragma unroll
            for (int k = 0; k < 4; ++k) {
                float4 c3;
                c3.x = k0 * (rr[k].x + rr[k+4].x) + k1 * (rr[k+1].x + rr[k+3].x) + k2 * rr[k+2].x;
                c3.y = k0 * (rr[k].y + rr[k+4].y) + k1 * (rr[k+1].y + rr[k+3].y) + k2 * rr[k+2].y;
                c3.z = k0 * (rr[k].z + rr[k+4].z) + k1 * (rr[k+1].z + rr[k+3].z) + k2 * rr[k+2].z;
                c3.w = k0 * (rr[k].w + rr[k+4].w) + k1 * (rr[k+1].w + rr[k+3].w) + k2 * rr[k+2].w;
                const int y = -16 + c + 4 * (4 * g + k); // [-16,80)
                const int slot = (y + 24) * SA + h + 2;
                float4 old = A4[slot];                    // coarse2 (own slot)
                A4[slot] = c3;
                if (y >= 0 && y < 64 && h >= 4 && h < 12)
                    *(float4*)(det2 + (long)(by + y) * W + bx + 4 * h - 16) = f4sub(old, c3);
            }
        }
    }
    __syncthreads();

    // ---- s3 h-pass (D=8): coarse3 rows [-16,80) (A rows 8..103), out x = 4*h3 ----
    for (int t = tid; t < 96 * 8; t += NT) {
        int r2 = t / 8, h3 = t - r2 * 8;
        int arow = r2 + 8;
        int base = arow * SA + h3;
        float4 t0 = A4[base + 2], t1 = A4[base + 4], t2 = A4[base + 6], t3 = A4[base + 8], t4 = A4[base + 10];
        float4 o;
        o.x = k0 * (t0.x + t4.x) + k1 * (t1.x + t3.x) + k2 * t2.x;
        o.y = k0 * (t0.y + t4.y) + k1 * (t1.y + t3.y) + k2 * t2.y;
        o.z = k0 * (t0.z + t4.z) + k1 * (t1.z + t3.z) + k2 * t2.z;
        o.w = k0 * (t0.w + t4.w) + k1 * (t1.w + t3.w) + k2 * t2.w;
        B4[arow * SB + h3] = o;
    }
    __syncthreads();

    // ---- s3 v-pass (D=8): 128 groups ----
    if (tid < 128) {
        const int h3 = tid & 7, u = tid >> 3;
        const int c = u & 7, g = u >> 3;                 // c in [0,8), g in [0,2)
        float4 rr[8];
        #pragma unroll
        for (int m = 0; m < 8; ++m) rr[m] = B4[(8 + c + 32 * g + 8 * m) * SB + h3];
        float* det3 = out + (long)tb * OB + 3 * HW;
        float* coa4 = out + (long)tb * OB + 4 * HW;
        #pragma unroll
        for (int k = 0; k < 4; ++k) {
            float4 c4;
            c4.x = k0 * (rr[k].x + rr[k+4].x) + k1 * (rr[k+1].x + rr[k+3].x) + k2 * rr[k+2].x;
            c4.y = k0 * (rr[k].y + rr[k+4].y) + k1 * (rr[k+1].y + rr[k+3].y) + k2 * rr[k+2].y;
            c4.z = k0 * (rr[k].z + rr[k+4].z) + k1 * (rr[k+1].z + rr[k+3].z) + k2 * rr[k+2].z;
            c4.w = k0 * (rr[k].w + rr[k+4].w) + k1 * (rr[k+1].w + rr[k+3].w) + k2 * rr[k+2].w;
            const int y = c + 8 * (4 * g + k);           // [0,64)
            float4 old = A4[(y + 24) * SA + h3 + 6];     // coarse3
            const long gofs = (long)(by + y) * W + bx + 4 * h3;
            *(float4*)(det3 + gofs) = f4sub(old, c4);
            *(float4*)(coa4 + gofs) = c4;
        }
    }
}

extern "C" void kernel_launch(void* const* d_in, const int* in_sizes, int n_in,
                              void* d_out, int out_size, void* d_ws, size_t ws_size,
                              hipStream_t stream) {
    const float* x = (const float*)d_in[0];
    float* out = (float*)d_out;
    float* ws  = (float*)d_ws;   // coarse2 buffer: 16*1024*1024 floats = 64 MiB
    (void)in_sizes; (void)n_in; (void)ws_size; (void)out_size;

    dim3 gA(16, 16, 16), gB(32, 16, 16);
    starlet_s01<<<gA, dim3(NT), 0, stream>>>(x, out, ws);
    starlet_s23<<<gB, dim3(NT), 0, stream>>>(ws, out);
}

// Round 4
// 483.920 us; speedup vs baseline: 1.0573x; 1.0413x over previous
//
#include <hip/hip_runtime.h>

// Fused 4-scale starlet transform (round-1 best, 478.5 us) + XCD-chunked
// block swizzle. ONE kernel, whole cascade in LDS:
// - 64x64 output tile per block, halo 32 (cumulative radius 30, vec4-rounded).
// - Region 128x128 floats in LDS buffer A (coarse, updated in place per scale);
//   buffer B holds the horizontal-pass intermediate.
// - HBM traffic = compulsory only: 67 MB read + 335 MB write. Measured model:
//   dur ~= 2 harness poison-fills (~430 us) + ~50 us kernel -> at the floor.
// - XCD swizzle: consecutive resident blocks on one XCD are spatial neighbors,
//   so the 4x halo-overlapped input fetches hit that XCD's L2 (T1 regime).

constexpr int H  = 1024, W = 1024;
constexpr int TS = 64;          // output tile
constexpr int HALO = 32;        // >= 2*(1+2+4+8) = 30, vec4-aligned
constexpr int RW = 128;         // region = TS + 2*HALO
constexpr int LSV = 33;         // LDS row stride in float4 (132 floats: +4 pad)
constexpr int NT = 1024;        // threads per block

static_assert(2 * RW * LSV * 16 <= 160 * 1024, "LDS budget");

__device__ __forceinline__ int reflect_i(int g, int n) {
    g = (g < 0) ? -g : g;
    return (g >= n) ? (2 * n - 2 - g) : g;
}

// Bijective XCD-chunked swizzle; nwg = 16*16*16 = 4096, divisible by 8.
__device__ __forceinline__ void swizzle_wg(int& tx, int& ty, int& tb) {
    const int gx = 16, gy = 16;
    const int nwg = gx * gy * (int)gridDim.z;
    const int lin = (int)blockIdx.x + gx * ((int)blockIdx.y + gy * (int)blockIdx.z);
    const int work = (lin & 7) * (nwg >> 3) + (lin >> 3);
    tx = work % gx;
    const int rest = work / gx;
    ty = rest % gy;
    tb = rest / gy;
}

template<int D>
__device__ __forceinline__ void scale_pass(float4* __restrict__ A4, float4* __restrict__ B4,
                                           int tid, int bx, int by,
                                           float* __restrict__ det, float* __restrict__ coa)
{
    const float k0 = 0.0625f, k1 = 0.25f, k2 = 0.375f;
    constexpr int Q  = 32 - 2 * D;       // vec4 columns per row this scale
    constexpr int HR = RW - 4 * D;       // htmp rows: [2D, 128-2D)
    constexpr int HTASKS = HR * Q;

    // ---- horizontal 5-tap (dilated): A -> B ----
    for (int t = tid; t < HTASKS; t += NT) {
        int r    = 2 * D + t / Q;
        int qx   = D + t % Q;            // x = 4*qx, x in [4D, 128-4D)
        int base = r * LSV + qx;
        float4 o;
        if constexpr (D >= 4) {
            // taps at x + (j-2)*D are vec4-aligned for D=4,8
            float4 t0 = A4[base - D / 2];
            float4 t1 = A4[base - D / 4];
            float4 t2 = A4[base];
            float4 t3 = A4[base + D / 4];
            float4 t4 = A4[base + D / 2];
            o.x = k0 * (t0.x + t4.x) + k1 * (t1.x + t3.x) + k2 * t2.x;
            o.y = k0 * (t0.y + t4.y) + k1 * (t1.y + t3.y) + k2 * t2.y;
            o.z = k0 * (t0.z + t4.z) + k1 * (t1.z + t3.z) + k2 * t2.z;
            o.w = k0 * (t0.w + t4.w) + k1 * (t1.w + t3.w) + k2 * t2.w;
        } else {
            // span [x-4, x+8) covers taps for D=1 (x±2) and D=2 (x±4)
            float4 v0 = A4[base - 1], v1 = A4[base], v2 = A4[base + 1];
            float f[12] = {v0.x, v0.y, v0.z, v0.w,
                           v1.x, v1.y, v1.z, v1.w,
                           v2.x, v2.y, v2.z, v2.w};
            float oo[4];
            #pragma unroll
            for (int i = 0; i < 4; ++i) {
                if constexpr (D == 1)
                    oo[i] = k0 * (f[i + 2] + f[i + 6]) + k1 * (f[i + 3] + f[i + 5]) + k2 * f[i + 4];
                else
                    oo[i] = k0 * (f[i]     + f[i + 8]) + k1 * (f[i + 2] + f[i + 6]) + k2 * f[i + 4];
            }
            o.x = oo[0]; o.y = oo[1]; o.z = oo[2]; o.w = oo[3];
        }
        B4[base] = o;
    }
    __syncthreads();

    // ---- vertical 5-tap, 4-row register blocking: B -> A (in place) ----
    constexpr int NC = RW / D - 8;       // rows per residue class in [4D, 128-4D)
    constexpr int GR = NC / 4;           // 4-row groups per class
    constexpr int VTASKS = D * GR * Q;
    for (int t = tid; t < VTASKS; t += NT) {
        int q  = t % Q;
        int u  = t / Q;
        int c  = u % D;                  // residue class
        int g  = u / D;                  // group within class
        int qx = D + q;
        float4 rr[8];
        #pragma unroll
        for (int m = 0; m < 8; ++m) {
            int r = 4 * D + c + (4 * g + m - 2) * D;   // htmp rows, all in [2D, 128-2D)
            rr[m] = B4[r * LSV + qx];
        }
        #pragma unroll
        for (int k = 0; k < 4; ++k) {
            float4 acc;
            acc.x = k0 * (rr[k].x + rr[k+4].x) + k1 * (rr[k+1].x + rr[k+3].x) + k2 * rr[k+2].x;
            acc.y = k0 * (rr[k].y + rr[k+4].y) + k1 * (rr[k+1].y + rr[k+3].y) + k2 * rr[k+2].y;
            acc.z = k0 * (rr[k].z + rr[k+4].z) + k1 * (rr[k+1].z + rr[k+3].z) + k2 * rr[k+2].z;
            acc.w = k0 * (rr[k].w + rr[k+4].w) + k1 * (rr[k+1].w + rr[k+3].w) + k2 * rr[k+2].w;
            int r  = 4 * D + c + (4 * g + k) * D;
            int ai = r * LSV + qx;
            int x  = 4 * qx;
            bool center = (r >= HALO) && (r < HALO + TS) && (x >= HALO) && (x < HALO + TS);
            if (center) {
                float4 old = A4[ai];                   // coarse_s (read before overwrite)
                float4 d = {old.x - acc.x, old.y - acc.y, old.z - acc.z, old.w - acc.w};
                long gofs = (long)(by - HALO + r) * W + (bx - HALO + x);
                *(float4*)(det + gofs) = d;
                if constexpr (D == 8) *(float4*)(coa + gofs) = acc;
            }
            A4[ai] = acc;                              // A now holds coarse_{s+1}
        }
    }
    __syncthreads();
}

__global__ __launch_bounds__(NT)
void starlet_fused(const float* __restrict__ in, float* __restrict__ out)
{
    __shared__ float4 Abuf[RW * LSV];
    __shared__ float4 Bbuf[RW * LSV];
    float* A = (float*)Abuf;

    const int tid = threadIdx.x;
    int tx, ty, tb;
    swizzle_wg(tx, ty, tb);
    const int bx = tx * TS;
    const int by = ty * TS;
    const float* __restrict__ inp  = in  + (long)tb * H * W;
    float* __restrict__       outp = out + (long)tb * 5L * H * W;

    // ---- load region [by-32, by+96) x [bx-32, bx+96) into A ----
    const bool interior = (bx >= HALO) && (bx + TS + HALO <= W) &&
                          (by >= HALO) && (by + TS + HALO <= H);
    if (interior) {
        const float* src = inp + (long)(by - HALO) * W + (bx - HALO);
        #pragma unroll
        for (int k = 0; k < 4; ++k) {
            int idx = tid + k * NT;              // 4096 vec4 = 128 rows x 32 vec4
            int r   = idx >> 5;
            int cq  = idx & 31;
            Abuf[r * LSV + cq] = *(const float4*)(src + (long)r * W + 4 * cq);
        }
    } else {
        #pragma unroll
        for (int k = 0; k < 16; ++k) {
            int idx = tid + k * NT;              // 16384 scalar loads with reflect
            int r   = idx >> 7;
            int cc  = idx & 127;
            int gy  = reflect_i(by - HALO + r, H);
            int gx  = reflect_i(bx - HALO + cc, W);
            A[r * (4 * LSV) + cc] = inp[(long)gy * W + gx];
        }
    }
    __syncthreads();

    // cascade: A always holds current coarse; valid region shrinks 2D per side per scale
    scale_pass<1>(Abuf, Bbuf, tid, bx, by, outp + 0L * H * W, nullptr);
    scale_pass<2>(Abuf, Bbuf, tid, bx, by, outp + 1L * H * W, nullptr);
    scale_pass<4>(Abuf, Bbuf, tid, bx, by, outp + 2L * H * W, nullptr);
    scale_pass<8>(Abuf, Bbuf, tid, bx, by, outp + 3L * H * W, outp + 4L * H * W);
}

extern "C" void kernel_launch(void* const* d_in, const int* in_sizes, int n_in,
                              void* d_out, int out_size, void* d_ws, size_t ws_size,
                              hipStream_t stream) {
    const float* x = (const float*)d_in[0];
    float* out = (float*)d_out;
    (void)in_sizes; (void)n_in; (void)d_ws; (void)ws_size; (void)out_size;

    dim3 grid(W / TS, H / TS, 16);
    dim3 block(NT);
    starlet_fused<<<grid, block, 0, stream>>>(x, out);
}